// Round 4
// baseline (165.162 us; speedup 1.0000x reference)
//
#include <hip/hip_runtime.h>

// Problem dims (hard-coded in reference)
#define DD   768
#define NN   512
#define MM   512

#define PRE_K 2.88539008177792681472f   // 2*log2(e)

__device__ __forceinline__ float fexp(float x) { return __builtin_amdgcn_exp2f(x); }
__device__ __forceinline__ float frcp(float x) { return __builtin_amdgcn_rcpf(x); }
// tanh(x) = 1 - 2/(1 + e^{2x}); saturates correctly via exp2->inf/0 + rcp.
__device__ __forceinline__ float fast_tanh(float x) {
  return 1.0f - 2.0f * frcp(fexp(PRE_K * x) + 1.0f);
}

// ---- 32x64 fp32 GEMM tile, double-buffered LDS, K-range, plain stores ------
// Smaller tile than R3's 64x64: same total FLOPs but 2x the blocks ->
// 4+ waves/SIMD for latency hiding (R2/R3 lesson: these GEMMs are
// latency-bound, VALUBusy 17% at 2.25 waves/SIMD).
// Out[i,j] = sum_k Xeff[i,k] * (TRANSB ? W[j,k] : W[k,j]),
// Xeff = XSUM2 ? X+X2 : X  (folds the A=P0+P1 reduction into cgemm staging).
#define XLD 34   // 32+2: keeps 8B align for b64 reads, breaks pow2 banks
#define WLD 68   // 64+4: keeps 16B align for b128 reads (68*4=272=16*17)

template <bool TRANSB, bool XSUM2>
__device__ __forceinline__ void gemm_tile32(
    const float* __restrict__ X, const float* __restrict__ X2,
    const float* __restrict__ W,
    float* __restrict__ Out, int ldo,
    int i0, int j0, int ldx, int ldw, int k0, int ksteps)
{
  __shared__ float Xs[2][16][XLD];   // [buf][k][row]
  __shared__ float Ws[2][16][WLD];   // [buf][k][col]
  const int tid  = threadIdx.x;
  // X staging: 32 rows x 16 k = 512 floats, one float2 per thread
  const int xrow = tid >> 3;            // 0..31
  const int xk   = (tid & 7) << 1;      // 0,2,..,14
  const float* xp  = &X[(size_t)(i0 + xrow) * ldx + k0 + xk];
  const float* xp2 = XSUM2 ? &X2[(size_t)(i0 + xrow) * ldx + k0 + xk] : nullptr;
  // W staging: 16 k x 64 cols = 1024 floats, one float4 per thread
  const float* wp = TRANSB
      ? &W[(size_t)(j0 + (tid >> 2)) * ldw + k0 + ((tid & 3) << 2)]
      : &W[(size_t)(k0 + (tid >> 4)) * ldw + j0 + ((tid & 15) << 2)];

  const int ng = tid >> 4;     // 0..15 -> rows 2ng, 2ng+1
  const int mg = tid & 15;     // 0..15 -> cols 4mg..4mg+3

  // prefetch step 0
  float2 xv = *(const float2*)xp;
  if (XSUM2) { const float2 t = *(const float2*)xp2; xv.x += t.x; xv.y += t.y; }
  float4 wv = *(const float4*)wp;

  float acc[2][4] = {};
  int p = 0;

  Xs[0][xk][xrow] = xv.x; Xs[0][xk + 1][xrow] = xv.y;
  if (TRANSB) {
    const int c = tid >> 2, kq = (tid & 3) << 2;
    Ws[0][kq + 0][c] = wv.x; Ws[0][kq + 1][c] = wv.y;
    Ws[0][kq + 2][c] = wv.z; Ws[0][kq + 3][c] = wv.w;
  } else {
    *(float4*)&Ws[0][tid >> 4][(tid & 15) << 2] = wv;
  }
  __syncthreads();

  for (int s = 0; s < ksteps; ++s) {
    const bool more = (s + 1 < ksteps);
    if (more) {
      xv = *(const float2*)(xp + (s + 1) * 16);
      if (XSUM2) {
        const float2 t = *(const float2*)(xp2 + (s + 1) * 16);
        xv.x += t.x; xv.y += t.y;
      }
      wv = TRANSB ? *(const float4*)(wp + (s + 1) * 16)
                  : *(const float4*)(wp + (size_t)(s + 1) * 16 * ldw);
    }
    #pragma unroll
    for (int kk = 0; kk < 16; ++kk) {
      const float2 xr = *(const float2*)&Xs[p][kk][ng << 1];
      const float4 wr = *(const float4*)&Ws[p][kk][mg << 2];
      acc[0][0] = fmaf(xr.x, wr.x, acc[0][0]);
      acc[0][1] = fmaf(xr.x, wr.y, acc[0][1]);
      acc[0][2] = fmaf(xr.x, wr.z, acc[0][2]);
      acc[0][3] = fmaf(xr.x, wr.w, acc[0][3]);
      acc[1][0] = fmaf(xr.y, wr.x, acc[1][0]);
      acc[1][1] = fmaf(xr.y, wr.y, acc[1][1]);
      acc[1][2] = fmaf(xr.y, wr.z, acc[1][2]);
      acc[1][3] = fmaf(xr.y, wr.w, acc[1][3]);
    }
    if (more) {
      const int q = p ^ 1;
      Xs[q][xk][xrow] = xv.x; Xs[q][xk + 1][xrow] = xv.y;
      if (TRANSB) {
        const int c = tid >> 2, kq = (tid & 3) << 2;
        Ws[q][kq + 0][c] = wv.x; Ws[q][kq + 1][c] = wv.y;
        Ws[q][kq + 2][c] = wv.z; Ws[q][kq + 3][c] = wv.w;
      } else {
        *(float4*)&Ws[q][tid >> 4][(tid & 15) << 2] = wv;
      }
    }
    __syncthreads();
    p ^= 1;
  }

  #pragma unroll
  for (int r = 0; r < 2; ++r) {
    float4 o;
    o.x = acc[r][0]; o.y = acc[r][1]; o.z = acc[r][2]; o.w = acc[r][3];
    *(float4*)&Out[(size_t)(i0 + (ng << 1) + r) * ldo + j0 + (mg << 2)] = o;
  }
}

// z = g*2 + ks. g 0: text@W1 -> P0/P1 ; 1: text@W2 -> P2/P3 ;
// 2: visual@W3^T -> P4/P5.  K split 2 (384 each). 12x16x6 = 1152 blocks.
__global__ __launch_bounds__(256) void gemm3_kernel(
    const float* __restrict__ text, const float* __restrict__ visual,
    const float* __restrict__ W1, const float* __restrict__ W2,
    const float* __restrict__ W3, float* __restrict__ P)
{
  const int i0 = blockIdx.y * 32;
  const int j0 = blockIdx.x * 64;
  const int z  = blockIdx.z;
  const int g  = z >> 1;
  const int k0 = (z & 1) * (DD / 2);
  float* Out = P + (size_t)z * NN * DD;
  if (g == 0)
    gemm_tile32<false, false>(text,  nullptr, W1, Out, DD, i0, j0, DD, DD, k0, 24);
  else if (g == 1)
    gemm_tile32<false, false>(text,  nullptr, W2, Out, DD, i0, j0, DD, DD, k0, 24);
  else
    gemm_tile32<true,  false>(visual, nullptr, W3, Out, DD, i0, j0, DD, DD, k0, 24);
}

// kw2t = PRE_K*(P2+P3) ; kw3v = PRE_K*(P4+P5)   (A handled inside cgemm)
__global__ __launch_bounds__(256) void reduce23_kernel(
    const float* __restrict__ P2, const float* __restrict__ P3,
    const float* __restrict__ P4, const float* __restrict__ P5,
    float* __restrict__ kw2t, float* __restrict__ kw3v)
{
  const size_t i = ((size_t)blockIdx.x * 256 + threadIdx.x) * 4;
  const float4 b0 = *(const float4*)&P2[i];
  const float4 b1 = *(const float4*)&P3[i];
  const float4 c0 = *(const float4*)&P4[i];
  const float4 c1 = *(const float4*)&P5[i];
  float4 o;
  o.x = PRE_K * (b0.x + b1.x); o.y = PRE_K * (b0.y + b1.y);
  o.z = PRE_K * (b0.z + b1.z); o.w = PRE_K * (b0.w + b1.w);
  *(float4*)&kw2t[i] = o;
  o.x = PRE_K * (c0.x + c1.x); o.y = PRE_K * (c0.y + c1.y);
  o.z = PRE_K * (c0.z + c1.z); o.w = PRE_K * (c0.w + c1.w);
  *(float4*)&kw3v[i] = o;
}

// Q[z] = (P0+P1) @ visual^T over K range z*96..+96. 8x16x8 = 1024 blocks.
__global__ __launch_bounds__(256) void cgemm_kernel(
    const float* __restrict__ P0, const float* __restrict__ P1,
    const float* __restrict__ visual, float* __restrict__ Q)
{
  const int i0 = blockIdx.y * 32;
  const int j0 = blockIdx.x * 64;
  const int z  = blockIdx.z;
  gemm_tile32<true, true>(P0, P1, visual, Q + (size_t)z * NN * MM, MM,
                          i0, j0, DD, DD, z * (DD / 8), 6);
}

// T[n] = sum_d text[n,d]  (for score = T[n] - 2*sum text*r identity)
__global__ __launch_bounds__(64) void tsum_kernel(
    const float* __restrict__ text, float* __restrict__ T)
{
  const int n = blockIdx.x;
  const int lane = threadIdx.x;
  float s = 0.f;
  #pragma unroll
  for (int i = 0; i < DD / 64; ++i) s += text[n * DD + lane + i * 64];
  #pragma unroll
  for (int off = 32; off; off >>= 1) s += __shfl_down(s, off);
  if (lane == 0) T[n] = s;
}

// ---- main fused kernel -----------------------------------------------------
// cval = tanh(sum_z Q[z][n,m])  (folds reducec)
// score[n,m] = T[n] - 2*sum_d text[n,d]*rcp(1 + exp2(kw2t[n,d] + kw3v[m,d]*cval))
// Tile 16n x 32m, 256 thr, each thread owns 2 m's -> ts/w2s LDS reads and
// staging traffic halved per element.
#define DCH  64          // d-chunk staged per iteration
#define MLDW 68          // LDS row stride (64+4, 16B-aligned)

__global__ __launch_bounds__(256) void main_kernel(
    const float* __restrict__ text, const float* __restrict__ kw2t,
    const float* __restrict__ kw3v, const float* __restrict__ Q,
    const float* __restrict__ T,    float* __restrict__ out)
{
  __shared__ float ts[16][MLDW];
  __shared__ float w2s[16][MLDW];
  __shared__ float w3s[32][MLDW];

  const int tid = threadIdx.x;
  const int nl = tid >> 4;            // 0..15
  const int ml = tid & 15;            // 0..15
  const int n0 = blockIdx.y * 16;
  const int m0 = blockIdx.x * 32;
  const int n  = n0 + nl;
  const int mA = m0 + ml, mB = mA + 16;

  // fold reducec: sum 8 Craw partials + tanh, per owned m
  float cA = 0.f, cB = 0.f;
  #pragma unroll
  for (int z = 0; z < 8; ++z) {
    const float* q = Q + (size_t)z * NN * MM + (size_t)n * MM;
    cA += q[mA]; cB += q[mB];
  }
  cA = fast_tanh(cA); cB = fast_tanh(cB);
  const float Tn = T[n];

  float4 aA = {0.f, 0.f, 0.f, 0.f};
  float4 aB = {0.f, 0.f, 0.f, 0.f};

  const int srow = tid >> 4;              // staging row 0..15
  const int sc4  = (tid & 15) << 2;       // staging col 0..60

  for (int d0 = 0; d0 < DD; d0 += DCH) {
    *(float4*)&ts[srow][sc4]       = *(const float4*)&text[(size_t)(n0 + srow) * DD + d0 + sc4];
    *(float4*)&w2s[srow][sc4]      = *(const float4*)&kw2t[(size_t)(n0 + srow) * DD + d0 + sc4];
    *(float4*)&w3s[srow][sc4]      = *(const float4*)&kw3v[(size_t)(m0 + srow) * DD + d0 + sc4];
    *(float4*)&w3s[srow + 16][sc4] = *(const float4*)&kw3v[(size_t)(m0 + 16 + srow) * DD + d0 + sc4];
    __syncthreads();

    #pragma unroll 4
    for (int j = 0; j < DCH; j += 4) {
      const float4 tv  = *(const float4*)&ts[nl][j];
      const float4 w2  = *(const float4*)&w2s[nl][j];
      const float4 w3A = *(const float4*)&w3s[ml][j];
      const float4 w3B = *(const float4*)&w3s[ml + 16][j];
      aA.x = fmaf(tv.x, frcp(fexp(fmaf(w3A.x, cA, w2.x)) + 1.0f), aA.x);
      aA.y = fmaf(tv.y, frcp(fexp(fmaf(w3A.y, cA, w2.y)) + 1.0f), aA.y);
      aA.z = fmaf(tv.z, frcp(fexp(fmaf(w3A.z, cA, w2.z)) + 1.0f), aA.z);
      aA.w = fmaf(tv.w, frcp(fexp(fmaf(w3A.w, cA, w2.w)) + 1.0f), aA.w);
      aB.x = fmaf(tv.x, frcp(fexp(fmaf(w3B.x, cB, w2.x)) + 1.0f), aB.x);
      aB.y = fmaf(tv.y, frcp(fexp(fmaf(w3B.y, cB, w2.y)) + 1.0f), aB.y);
      aB.z = fmaf(tv.z, frcp(fexp(fmaf(w3B.z, cB, w2.z)) + 1.0f), aB.z);
      aB.w = fmaf(tv.w, frcp(fexp(fmaf(w3B.w, cB, w2.w)) + 1.0f), aB.w);
    }
    __syncthreads();
  }

  out[(size_t)n * MM + mA] = Tn - 2.0f * ((aA.x + aA.y) + (aA.z + aA.w));
  out[(size_t)n * MM + mB] = Tn - 2.0f * ((aB.x + aB.y) + (aB.z + aB.w));
}

// ---- launcher --------------------------------------------------------------
extern "C" void kernel_launch(void* const* d_in, const int* in_sizes, int n_in,
                              void* d_out, int out_size, void* d_ws, size_t ws_size,
                              hipStream_t stream) {
  const float* text   = (const float*)d_in[0];
  const float* visual = (const float*)d_in[1];
  const float* W1     = (const float*)d_in[2];
  const float* W2     = (const float*)d_in[3];
  const float* W3     = (const float*)d_in[4];
  float* out = (float*)d_out;

  // Workspace layout (floats), S = NN*DD, Ssm = NN*MM:
  //   [0,S)      kw2t
  //   [S,2S)     kw3v
  //   [2S,8S)    P0..P5 (gemm3 partials)
  //   [4S,...)   Q0..Q7 (cgemm partials) -- REUSES P2..P5's region; safe
  //              because the stream serializes reduce23 (reads P2..P5)
  //              before cgemm (writes Q). Q must not overlap P0/P1 (read
  //              by cgemm): Q starts at 4S > 4S-1 end of P1. OK.
  //   [4S+8*Ssm) T (512 floats)
  // Total = 4S + 8*Ssm + 512 = 3,670,528 floats = 14.7 MB (R3 proved >=15.2 MB).
  const size_t S = (size_t)NN * DD, Ssm = (size_t)NN * MM;
  float* ws   = (float*)d_ws;
  float* kw2t = ws;
  float* kw3v = ws + S;
  float* P    = ws + 2 * S;          // P[z] = P + z*S, z=0..5
  float* Q    = ws + 4 * S;          // Q[z] = Q + z*Ssm, z=0..7
  float* T    = ws + 4 * S + 8 * Ssm;

  hipLaunchKernelGGL(tsum_kernel, dim3(NN), dim3(64), 0, stream, text, T);
  hipLaunchKernelGGL(gemm3_kernel, dim3(DD / 64, NN / 32, 6), dim3(256), 0, stream,
                     text, visual, W1, W2, W3, P);
  hipLaunchKernelGGL(reduce23_kernel, dim3(S / 1024), dim3(256), 0, stream,
                     P + 2 * S, P + 3 * S, P + 4 * S, P + 5 * S, kw2t, kw3v);
  hipLaunchKernelGGL(cgemm_kernel, dim3(MM / 64, NN / 32, 8), dim3(256), 0, stream,
                     P, P + S, visual, Q);
  hipLaunchKernelGGL(main_kernel, dim3(MM / 32, NN / 16), dim3(256), 0, stream,
                     text, kw2t, kw3v, Q, T, out);
}